// Round 2
// baseline (320.546 us; speedup 1.0000x reference)
//
#include <hip/hip_runtime.h>

#define NOUT 7
#define NROI 512
#define NCH 256
#define BINS (NOUT * NOUT)          // 49
#define ROI_ELEMS (NCH * BINS)      // 12544
#define CHB 8                       // channels per block
#define NCG (NCH / CHB)             // 32 channel-groups per roi
#define OUTS (CHB * BINS)           // 392 outputs per block
// Worst-case footprint: level selection bounds feature-area fw*fh < 784 with
// fw,fh <= 124; discrete max of rs*(cs|1) over that set is 1062 floats
// (fh=124, fw=6.3 skew). 1088 > 1062 is provably sufficient.
#define TILE_STRIDE 1088

__global__ __launch_bounds__(256) void roi_pool_kernel(
    const float* __restrict__ x2,
    const float* __restrict__ x3,
    const float* __restrict__ x4,
    const float* __restrict__ x5,
    const float* __restrict__ boxes,
    float* __restrict__ out)
{
    const int r  = blockIdx.x;   // roi 0..511
    const int cg = blockIdx.y;   // channel group 0..31
    const int t  = threadIdx.x;  // 0..255

    // per-channel compact footprint tiles (runtime stride forced odd -> no
    // row-stride bank aliasing on the 16 ds_read_b32 per output)
    __shared__ float tile[CHB][TILE_STRIDE];
    // per-ph: sdyA = {asint(rowoff_a), asint(rowoff_b), 0.25*va*(1-fya), 0.25*va*fya}
    //         sdyB = {0.25*vb*(1-fyb), 0.25*vb*fyb}   (rowoff = (i0 - ylo)*stride)
    // per-pw: sdxA = {asint(coloff_a), asint(coloff_b), va*(1-fxa), va*fxa}
    //         sdxB = {vb*(1-fxb), vb*fxb}             (coloff = i0 - xlo)
    __shared__ float4 sdyA[NOUT];
    __shared__ float2 sdyB[NOUT];
    __shared__ float4 sdxA[NOUT];
    __shared__ float2 sdxB[NOUT];
    __shared__ const float* s_src;  // feat + (b*NCH + cg*CHB)*HW + ylo*W + xlo
    __shared__ int s_W, s_HW, s_st, s_cs, s_pad;
    __shared__ unsigned s_M;        // ceil(2^32 / stride) for e -> row decomposition

    if (t < 32) {
        const float bx1 = boxes[4 * r + 0];
        const float by1 = boxes[4 * r + 1];
        const float bx2 = boxes[4 * r + 2];
        const float by2 = boxes[4 * r + 3];
        const float sz  = sqrtf((bx2 - bx1) * (by2 - by1));
        float lvlf = floorf(4.0f + log2f(sz / 224.0f + 1e-8f));
        lvlf = fminf(fmaxf(lvlf, 2.0f), 5.0f);
        const int level = (int)lvlf - 2;

        int H, W; float scale; const float* feat;
        if (level == 0)      { H = 200; W = 304; scale = 0.25f;    feat = x2; }
        else if (level == 1) { H = 100; W = 152; scale = 0.125f;   feat = x3; }
        else if (level == 2) { H = 50;  W = 76;  scale = 0.0625f;  feat = x4; }
        else                 { H = 25;  W = 38;  scale = 0.03125f; feat = x5; }

        const float X1 = bx1 * scale - 0.5f;
        const float Y1 = by1 * scale - 0.5f;
        const float X2 = bx2 * scale - 0.5f;
        const float Y2 = by2 * scale - 0.5f;
        const float bw = (X2 - X1) * (1.0f / NOUT);
        const float bh = (Y2 - Y1) * (1.0f / NOUT);

        // lanes 0..6: y-descriptors for ph = t; lanes 8..14: x-descriptors for
        // pw = t-8. All 32 lanes compute so the __shfl sources are valid.
        const bool isy = (t < 8);
        const int p    = min(isy ? t : (t - 8), 6);
        const int dim  = isy ? H : W;
        const float o0  = isy ? Y1 : X1;
        const float bsz = isy ? bh : bw;
        float ca = o0 + ((float)p + 0.25f) * bsz;
        float cb = o0 + ((float)p + 0.75f) * bsz;
        const float va = ((ca >= -1.0f) && (ca <= (float)dim)) ? 1.0f : 0.0f;
        const float vb = ((cb >= -1.0f) && (cb <= (float)dim)) ? 1.0f : 0.0f;
        ca = fminf(fmaxf(ca, 0.0f), (float)(dim - 1));
        cb = fminf(fmaxf(cb, 0.0f), (float)(dim - 1));
        const int ia = min((int)floorf(ca), dim - 2);   // taps ia, ia+1
        const int ib = min((int)floorf(cb), dim - 2);
        const float fa = ca - (float)ia;
        const float fb = cb - (float)ib;

        // footprint extents (sample positions are monotonic in p)
        const int ylo = __shfl(ia, 0);
        const int yhi = __shfl(ib, 6);
        const int xlo = __shfl(ia, 8);
        const int xhi = __shfl(ib, 14);
        const int cs = xhi + 2 - xlo;   // cols incl. +1 tap
        const int rs = yhi + 2 - ylo;   // rows incl. +1 tap
        const int st = cs | 1;          // odd LDS stride

        if (isy && t < 7) {
            sdyA[p] = make_float4(__int_as_float((ia - ylo) * st),
                                  __int_as_float((ib - ylo) * st),
                                  0.25f * va * (1.0f - fa), 0.25f * va * fa);
            sdyB[p] = make_float2(0.25f * vb * (1.0f - fb), 0.25f * vb * fb);
        } else if (!isy && t < 15) {
            sdxA[p] = make_float4(__int_as_float(ia - xlo),
                                  __int_as_float(ib - xlo),
                                  va * (1.0f - fa), va * fa);
            sdxB[p] = make_float2(vb * (1.0f - fb), vb * fb);
        } else if (t == 31) {
            const int HW = H * W;
            s_W   = W;
            s_HW  = HW;
            s_st  = st;
            s_cs  = cs;
            s_pad = min(rs * st, TILE_STRIDE);  // bound proven: rs*st <= 1062
            s_M   = (unsigned)(((1ull << 32) + (unsigned)st - 1) / (unsigned)st);
            s_src = feat + ((size_t)(r >> 8) * NCH + (size_t)cg * CHB) * HW
                         + (size_t)ylo * W + xlo;
        }
    }
    __syncthreads();

    // ---- stage: each 32-lane group loads one channel's footprint, compact ----
    {
        const int cl   = t >> 5;      // local channel 0..7
        const int lane = t & 31;
        const int W  = s_W;
        const int st = s_st;
        const int cs = s_cs;
        const int pad = s_pad;
        const unsigned M = s_M;
        const float* gsrc = s_src + (size_t)cl * s_HW;
        float* dst = tile[cl];
        for (int e = lane; e < pad; e += 32) {
            const int row = (int)__umulhi((unsigned)e, M);  // e / st
            const int col = e - row * st;
            // col == cs only on the odd-pad column; never read, guard the load
            dst[e] = (col < cs) ? gsrc[row * W + col] : 0.0f;
        }
    }
    __syncthreads();

    // ---- compute: 392 outputs per block from LDS ----
    const int st = s_st;
    float* const obase = out + (size_t)r * ROI_ELEMS + (size_t)cg * OUTS;
    for (int o = t; o < OUTS; o += 256) {
        const int cl  = o / BINS;
        const int bin = o - cl * BINS;
        const int ph  = bin / NOUT;
        const int pw  = bin - ph * NOUT;

        const float4 yA = sdyA[ph];
        const float2 yB = sdyB[ph];
        const float4 xA = sdxA[pw];
        const float2 xB = sdxB[pw];
        const int ro0 = __float_as_int(yA.x);
        const int ro1 = __float_as_int(yA.y);
        const int co0 = __float_as_int(xA.x);
        const int co1 = __float_as_int(xA.y);

        const float* Ta = tile[cl] + ro0;   // row iya       (+st -> iya+1)
        const float* Tb = tile[cl] + ro1;   // row iyb       (+st -> iyb+1)
        const float d0 = Ta[co0] * xA.z + Ta[co0 + 1] * xA.w
                       + Ta[co1] * xB.x + Ta[co1 + 1] * xB.y;
        const float d1 = Ta[st + co0] * xA.z + Ta[st + co0 + 1] * xA.w
                       + Ta[st + co1] * xB.x + Ta[st + co1 + 1] * xB.y;
        const float d2 = Tb[co0] * xA.z + Tb[co0 + 1] * xA.w
                       + Tb[co1] * xB.x + Tb[co1 + 1] * xB.y;
        const float d3 = Tb[st + co0] * xA.z + Tb[st + co0 + 1] * xA.w
                       + Tb[st + co1] * xB.x + Tb[st + co1 + 1] * xB.y;

        obase[o] = yA.z * d0 + yA.w * d1 + yB.x * d2 + yB.y * d3;
    }
}

extern "C" void kernel_launch(void* const* d_in, const int* in_sizes, int n_in,
                              void* d_out, int out_size, void* d_ws, size_t ws_size,
                              hipStream_t stream) {
    const float* x2    = (const float*)d_in[0];
    const float* x3    = (const float*)d_in[1];
    const float* x4    = (const float*)d_in[2];
    const float* x5    = (const float*)d_in[3];
    const float* boxes = (const float*)d_in[4];
    float* out = (float*)d_out;

    dim3 grid(NROI, NCG);
    roi_pool_kernel<<<grid, 256, 0, stream>>>(x2, x3, x4, x5, boxes, out);
}

// Round 3
// 251.647 us; speedup vs baseline: 1.2738x; 1.2738x over previous
//
#include <hip/hip_runtime.h>

#define NOUT 7
#define NROI 512
#define NCH 256
#define BINS (NOUT * NOUT)        // 49
#define ROI_ELEMS (NCH * BINS)    // 12544
#define KB 4                      // outputs per thread (memory-level parallelism)
#define CHUNK_EL (256 * KB)       // 1024 elements per block
#define NCHUNK ((ROI_ELEMS + CHUNK_EL - 1) / CHUNK_EL)  // 13

// float4 with 4-byte alignment: dword-aligned but not 16B-aligned loads
// (gfx950 handles this; validated in the previous session).
typedef float f4u __attribute__((ext_vector_type(4), aligned(4)));

__global__ __launch_bounds__(256, 4) void roi_pool_kernel(
    const float* __restrict__ x2,
    const float* __restrict__ x3,
    const float* __restrict__ x4,
    const float* __restrict__ x5,
    const float* __restrict__ boxes,
    float* __restrict__ out)
{
    const int r     = blockIdx.x;  // roi 0..511
    const int chunk = blockIdx.y;  // 0..12
    const int t     = threadIdx.x; // 0..255

    // y (per ph): sdyA = { asfloat(y0a*W), asfloat(y0b*W), rw0, rw1 },
    //             sdyB = { rw2, rw3 }   rw = 0.25*valid_y*{1-fy, fy} per sample
    // x fast (per pw): sdxW = xw[4] (both samples' lerp+valid weights in a
    //                  4-wide span), sdxC = span base xb
    // x slow (per pw): sdxP = { asfloat(ia), asfloat(ib), wa0, wa1 },
    //                  sdxQ = { wb0, wb1 }   (2-tap weights per x-sample)
    __shared__ float4 sdyA[NOUT];
    __shared__ float2 sdyB[NOUT];
    __shared__ float4 sdxW[NOUT];
    __shared__ int    sdxC[NOUT];
    __shared__ float4 sdxP[NOUT];
    __shared__ float2 sdxQ[NOUT];
    __shared__ int sfast;
    __shared__ const float* sbase;   // feat + b*C*H*W
    __shared__ int sW, sHW;

    if (t < 32) {
        const float bx1 = boxes[4 * r + 0];
        const float by1 = boxes[4 * r + 1];
        const float bx2 = boxes[4 * r + 2];
        const float by2 = boxes[4 * r + 3];
        const float sz  = sqrtf((bx2 - bx1) * (by2 - by1));
        float lvlf = floorf(4.0f + log2f(sz / 224.0f + 1e-8f));
        lvlf = fminf(fmaxf(lvlf, 2.0f), 5.0f);
        const int level = (int)lvlf - 2;

        int H, W; float scale; const float* feat;
        if (level == 0)      { H = 200; W = 304; scale = 0.25f;    feat = x2; }
        else if (level == 1) { H = 100; W = 152; scale = 0.125f;   feat = x3; }
        else if (level == 2) { H = 50;  W = 76;  scale = 0.0625f;  feat = x4; }
        else                 { H = 25;  W = 38;  scale = 0.03125f; feat = x5; }

        const float X1 = bx1 * scale - 0.5f;
        const float Y1 = by1 * scale - 0.5f;
        const float X2 = bx2 * scale - 0.5f;
        const float Y2 = by2 * scale - 0.5f;
        const float bw = (X2 - X1) * (1.0f / NOUT);
        const float bh = (Y2 - Y1) * (1.0f / NOUT);

        bool okl = true;   // per-lane fast-path fitness (x lanes only)

        if (t < NOUT) {
            // y descriptors for output row ph = t (samples at ph+0.25, ph+0.75)
            const int ph = t;
            float ca = Y1 + ((float)ph + 0.25f) * bh;
            float cb = Y1 + ((float)ph + 0.75f) * bh;
            const float va = ((ca >= -1.0f) && (ca <= (float)H)) ? 0.25f : 0.0f;
            const float vb = ((cb >= -1.0f) && (cb <= (float)H)) ? 0.25f : 0.0f;
            ca = fminf(fmaxf(ca, 0.0f), (float)(H - 1));
            cb = fminf(fmaxf(cb, 0.0f), (float)(H - 1));
            const int ia = min((int)floorf(ca), H - 2);   // i1 = i0+1 normalization
            const int ib = min((int)floorf(cb), H - 2);
            const float fya = ca - (float)ia;
            const float fyb = cb - (float)ib;
            sdyA[ph] = make_float4(__int_as_float(ia * W), __int_as_float(ib * W),
                                   va * (1.0f - fya), va * fya);
            sdyB[ph] = make_float2(vb * (1.0f - fyb), vb * fyb);
        } else if (t >= 8 && t < 8 + NOUT) {
            // x descriptors for output col pw = t-8
            const int pw = t - 8;
            float ca = X1 + ((float)pw + 0.25f) * bw;
            float cb = X1 + ((float)pw + 0.75f) * bw;
            const float va = ((ca >= -1.0f) && (ca <= (float)W)) ? 1.0f : 0.0f;
            const float vb = ((cb >= -1.0f) && (cb <= (float)W)) ? 1.0f : 0.0f;
            ca = fminf(fmaxf(ca, 0.0f), (float)(W - 1));
            cb = fminf(fmaxf(cb, 0.0f), (float)(W - 1));
            const int ia = min((int)floorf(ca), W - 2);
            const int ib = min((int)floorf(cb), W - 2);
            const float fxa = ca - (float)ia;
            const float fxb = cb - (float)ib;

            // slow-path descriptors (always valid)
            sdxP[pw] = make_float4(__int_as_float(ia), __int_as_float(ib),
                                   va * (1.0f - fxa), va * fxa);
            sdxQ[pw] = make_float2(vb * (1.0f - fxb), vb * fxb);

            // fast-path descriptors (valid iff both patches fit [xb, xb+3])
            const int xb = min(ia, W - 4);
            const int d0 = ia - xb;          // 0..2
            const int d1 = ib - xb;          // >= d0; fast iff <= 2
            okl = (d1 <= 2);
            float xw[4];
            #pragma unroll
            for (int k = 0; k < 4; ++k) {
                float w = 0.0f;
                w += va * ((k == d0) ? (1.0f - fxa) : (k == d0 + 1) ? fxa : 0.0f);
                w += vb * ((k == d1) ? (1.0f - fxb) : (k == d1 + 1) ? fxb : 0.0f);
                xw[k] = w;
            }
            sdxW[pw] = make_float4(xw[0], xw[1], xw[2], xw[3]);
            sdxC[pw] = xb;
        }

        // collect per-pw fitness (lanes 8..14); inactive lanes contribute 0
        const unsigned long long bal = __ballot(okl);
        if (t == 31) {
            const int b = r >> 8;
            sbase = feat + (size_t)b * NCH * H * W;
            sW    = W;
            sHW   = H * W;
            sfast = (((bal >> 8) & 0x7Full) == 0x7Full);
        }
    }
    __syncthreads();

    const float* const base = sbase;
    const int W  = sW;
    const int HW = sHW;
    const int i0 = chunk * CHUNK_EL + t;
    float* const obase = out + (size_t)r * ROI_ELEMS;

    if (sfast) {
        f4u    r0[KB], r1[KB], r2[KB], r3[KB];
        float4 yAv[KB], xwv[KB];
        float2 yBv[KB];
        #pragma unroll
        for (int k = 0; k < KB; ++k) {
            const int i = i0 + k * 256;
            if (i < ROI_ELEMS) {             // uniform per (block,k)
                const int c   = i / BINS;
                const int bin = i - c * BINS;
                const int ph  = bin / NOUT;
                const int pw  = bin - ph * NOUT;
                yAv[k] = sdyA[ph];
                yBv[k] = sdyB[ph];
                xwv[k] = sdxW[pw];
                const int xb = sdxC[pw];
                const float* const f  = base + (size_t)c * HW;
                const float* const pa = f + __float_as_int(yAv[k].x);
                const float* const pb = f + __float_as_int(yAv[k].y);
                r0[k] = *(const f4u*)(pa + xb);
                r1[k] = *(const f4u*)(pa + W + xb);
                r2[k] = *(const f4u*)(pb + xb);
                r3[k] = *(const f4u*)(pb + W + xb);
            }
        }
        #pragma unroll
        for (int k = 0; k < KB; ++k) {
            const int i = i0 + k * 256;
            if (i < ROI_ELEMS) {
                const float4 xw = xwv[k];
                const float d0 = r0[k].x * xw.x + r0[k].y * xw.y + r0[k].z * xw.z + r0[k].w * xw.w;
                const float d1 = r1[k].x * xw.x + r1[k].y * xw.y + r1[k].z * xw.z + r1[k].w * xw.w;
                const float d2 = r2[k].x * xw.x + r2[k].y * xw.y + r2[k].z * xw.z + r2[k].w * xw.w;
                const float d3 = r3[k].x * xw.x + r3[k].y * xw.y + r3[k].z * xw.z + r3[k].w * xw.w;
                obase[i] = yAv[k].z * d0 + yAv[k].w * d1 + yBv[k].x * d2 + yBv[k].y * d3;
            }
        }
    } else {
        float2 a0[KB], b0[KB], a1[KB], b1[KB], a2[KB], b2[KB], a3[KB], b3[KB];
        float4 yAv[KB], xpv[KB];
        float2 yBv[KB], xqv[KB];
        #pragma unroll
        for (int k = 0; k < KB; ++k) {
            const int i = i0 + k * 256;
            if (i < ROI_ELEMS) {
                const int c   = i / BINS;
                const int bin = i - c * BINS;
                const int ph  = bin / NOUT;
                const int pw  = bin - ph * NOUT;
                yAv[k] = sdyA[ph];
                yBv[k] = sdyB[ph];
                xpv[k] = sdxP[pw];
                xqv[k] = sdxQ[pw];
                const int ia = __float_as_int(xpv[k].x);
                const int ib = __float_as_int(xpv[k].y);
                const float* const f  = base + (size_t)c * HW;
                const float* const pa = f + __float_as_int(yAv[k].x);
                const float* const pb = f + __float_as_int(yAv[k].y);
                a0[k] = *(const float2*)(pa + ia);
                b0[k] = *(const float2*)(pa + ib);
                a1[k] = *(const float2*)(pa + W + ia);
                b1[k] = *(const float2*)(pa + W + ib);
                a2[k] = *(const float2*)(pb + ia);
                b2[k] = *(const float2*)(pb + ib);
                a3[k] = *(const float2*)(pb + W + ia);
                b3[k] = *(const float2*)(pb + W + ib);
            }
        }
        #pragma unroll
        for (int k = 0; k < KB; ++k) {
            const int i = i0 + k * 256;
            if (i < ROI_ELEMS) {
                const float4 xp = xpv[k];
                const float2 xq = xqv[k];
                const float d0 = a0[k].x * xp.z + a0[k].y * xp.w + b0[k].x * xq.x + b0[k].y * xq.y;
                const float d1 = a1[k].x * xp.z + a1[k].y * xp.w + b1[k].x * xq.x + b1[k].y * xq.y;
                const float d2 = a2[k].x * xp.z + a2[k].y * xp.w + b2[k].x * xq.x + b2[k].y * xq.y;
                const float d3 = a3[k].x * xp.z + a3[k].y * xp.w + b3[k].x * xq.x + b3[k].y * xq.y;
                obase[i] = yAv[k].z * d0 + yAv[k].w * d1 + yBv[k].x * d2 + yBv[k].y * d3;
            }
        }
    }
}

extern "C" void kernel_launch(void* const* d_in, const int* in_sizes, int n_in,
                              void* d_out, int out_size, void* d_ws, size_t ws_size,
                              hipStream_t stream) {
    const float* x2    = (const float*)d_in[0];
    const float* x3    = (const float*)d_in[1];
    const float* x4    = (const float*)d_in[2];
    const float* x5    = (const float*)d_in[3];
    const float* boxes = (const float*)d_in[4];
    float* out = (float*)d_out;

    dim3 grid(NROI, NCHUNK);
    roi_pool_kernel<<<grid, 256, 0, stream>>>(x2, x3, x4, x5, boxes, out);
}

// Round 4
// 229.559 us; speedup vs baseline: 1.3964x; 1.0962x over previous
//
#include <hip/hip_runtime.h>

#define NOUT 7
#define NROI 512
#define NCH 256
#define BINS (NOUT * NOUT)        // 49
#define ROI_ELEMS (NCH * BINS)    // 12544
#define PAIR_EL (NCH / 2 * BINS)  // 6272 (channel-pair, bin) items per roi
#define NCHUNK ((PAIR_EL + 255) / 256)  // 25

// float4 with 4-byte alignment: dword-aligned but not 16B-aligned loads
// (gfx950 handles this; validated in an earlier session).
typedef float f4u __attribute__((ext_vector_type(4), aligned(4)));

__global__ __launch_bounds__(256, 4) void roi_pool_kernel(
    const float* __restrict__ x2,
    const float* __restrict__ x3,
    const float* __restrict__ x4,
    const float* __restrict__ x5,
    const float* __restrict__ boxes,
    float* __restrict__ out)
{
    const int r     = blockIdx.x;  // roi 0..511
    const int chunk = blockIdx.y;  // 0..24
    const int t     = threadIdx.x; // 0..255

    // y (per ph): sdyA = { asfloat(y0a*W), asfloat(y0b*W), rw0, rw1 },
    //             sdyB = { rw2, rw3 }   rw = 0.25*valid_y*{1-fy, fy} per sample
    // x fast (per pw): sdxW = xw[4] (both samples' lerp+valid weights in a
    //                  4-wide span), sdxC = span base xb
    // x slow (per pw): sdxP = { asfloat(ia), asfloat(ib), wa0, wa1 },
    //                  sdxQ = { wb0, wb1 }   (2-tap weights per x-sample)
    __shared__ float4 sdyA[NOUT];
    __shared__ float2 sdyB[NOUT];
    __shared__ float4 sdxW[NOUT];
    __shared__ int    sdxC[NOUT];
    __shared__ float4 sdxP[NOUT];
    __shared__ float2 sdxQ[NOUT];
    __shared__ int sfast;
    __shared__ const float* sbase;   // feat + b*C*H*W
    __shared__ int sW, sHW;

    if (t < 32) {
        const float bx1 = boxes[4 * r + 0];
        const float by1 = boxes[4 * r + 1];
        const float bx2 = boxes[4 * r + 2];
        const float by2 = boxes[4 * r + 3];
        const float sz  = sqrtf((bx2 - bx1) * (by2 - by1));
        float lvlf = floorf(4.0f + log2f(sz / 224.0f + 1e-8f));
        lvlf = fminf(fmaxf(lvlf, 2.0f), 5.0f);
        const int level = (int)lvlf - 2;

        int H, W; float scale; const float* feat;
        if (level == 0)      { H = 200; W = 304; scale = 0.25f;    feat = x2; }
        else if (level == 1) { H = 100; W = 152; scale = 0.125f;   feat = x3; }
        else if (level == 2) { H = 50;  W = 76;  scale = 0.0625f;  feat = x4; }
        else                 { H = 25;  W = 38;  scale = 0.03125f; feat = x5; }

        const float X1 = bx1 * scale - 0.5f;
        const float Y1 = by1 * scale - 0.5f;
        const float X2 = bx2 * scale - 0.5f;
        const float Y2 = by2 * scale - 0.5f;
        const float bw = (X2 - X1) * (1.0f / NOUT);
        const float bh = (Y2 - Y1) * (1.0f / NOUT);

        bool okl = true;   // per-lane fast-path fitness (x lanes only)

        if (t < NOUT) {
            // y descriptors for output row ph = t (samples at ph+0.25, ph+0.75)
            const int ph = t;
            float ca = Y1 + ((float)ph + 0.25f) * bh;
            float cb = Y1 + ((float)ph + 0.75f) * bh;
            const float va = ((ca >= -1.0f) && (ca <= (float)H)) ? 0.25f : 0.0f;
            const float vb = ((cb >= -1.0f) && (cb <= (float)H)) ? 0.25f : 0.0f;
            ca = fminf(fmaxf(ca, 0.0f), (float)(H - 1));
            cb = fminf(fmaxf(cb, 0.0f), (float)(H - 1));
            const int ia = min((int)floorf(ca), H - 2);   // i1 = i0+1 normalization
            const int ib = min((int)floorf(cb), H - 2);
            const float fya = ca - (float)ia;
            const float fyb = cb - (float)ib;
            sdyA[ph] = make_float4(__int_as_float(ia * W), __int_as_float(ib * W),
                                   va * (1.0f - fya), va * fya);
            sdyB[ph] = make_float2(vb * (1.0f - fyb), vb * fyb);
        } else if (t >= 8 && t < 8 + NOUT) {
            // x descriptors for output col pw = t-8
            const int pw = t - 8;
            float ca = X1 + ((float)pw + 0.25f) * bw;
            float cb = X1 + ((float)pw + 0.75f) * bw;
            const float va = ((ca >= -1.0f) && (ca <= (float)W)) ? 1.0f : 0.0f;
            const float vb = ((cb >= -1.0f) && (cb <= (float)W)) ? 1.0f : 0.0f;
            ca = fminf(fmaxf(ca, 0.0f), (float)(W - 1));
            cb = fminf(fmaxf(cb, 0.0f), (float)(W - 1));
            const int ia = min((int)floorf(ca), W - 2);
            const int ib = min((int)floorf(cb), W - 2);
            const float fxa = ca - (float)ia;
            const float fxb = cb - (float)ib;

            // slow-path descriptors (always valid)
            sdxP[pw] = make_float4(__int_as_float(ia), __int_as_float(ib),
                                   va * (1.0f - fxa), va * fxa);
            sdxQ[pw] = make_float2(vb * (1.0f - fxb), vb * fxb);

            // fast-path descriptors (valid iff both patches fit [xb, xb+3])
            const int xb = min(ia, W - 4);
            const int d0 = ia - xb;          // 0..2
            const int d1 = ib - xb;          // >= d0; fast iff <= 2
            okl = (d1 <= 2);
            float xw[4];
            #pragma unroll
            for (int k = 0; k < 4; ++k) {
                float w = 0.0f;
                w += va * ((k == d0) ? (1.0f - fxa) : (k == d0 + 1) ? fxa : 0.0f);
                w += vb * ((k == d1) ? (1.0f - fxb) : (k == d1 + 1) ? fxb : 0.0f);
                xw[k] = w;
            }
            sdxW[pw] = make_float4(xw[0], xw[1], xw[2], xw[3]);
            sdxC[pw] = xb;
        }

        // collect per-pw fitness (lanes 8..14); inactive lanes contribute 0
        const unsigned long long bal = __ballot(okl);
        if (t == 31) {
            const int b = r >> 8;
            sbase = feat + (size_t)b * NCH * H * W;
            sW    = W;
            sHW   = H * W;
            sfast = (((bal >> 8) & 0x7Full) == 0x7Full);
        }
    }
    __syncthreads();

    const int j = chunk * 256 + t;          // (channel-pair, bin) index
    if (j >= PAIR_EL) return;

    const float* const base = sbase;
    const int W  = sW;
    const int HW = sHW;

    const int cp  = j / BINS;               // channel pair 0..127
    const int bin = j - cp * BINS;          // 0..48
    const int ph  = bin / NOUT;
    const int pw  = bin - ph * NOUT;

    const float4 yA = sdyA[ph];
    const float2 yB = sdyB[ph];

    const float* const f0 = base + (size_t)(2 * cp) * HW;   // channel c
    const float* const pa = f0 + __float_as_int(yA.x);      // row y0a, chan c
    const float* const pb = f0 + __float_as_int(yA.y);      // row y0b, chan c
    // channel c+1 rows are pa+HW / pb+HW

    float o0, o1;
    if (sfast) {
        const float4 xw = sdxW[pw];
        const int    xb = sdxC[pw];
        // 8 independent 16B loads in flight (no arrays -> no scratch)
        const f4u A0 = *(const f4u*)(pa + xb);
        const f4u A1 = *(const f4u*)(pa + W + xb);
        const f4u A2 = *(const f4u*)(pb + xb);
        const f4u A3 = *(const f4u*)(pb + W + xb);
        const f4u B0 = *(const f4u*)(pa + HW + xb);
        const f4u B1 = *(const f4u*)(pa + HW + W + xb);
        const f4u B2 = *(const f4u*)(pb + HW + xb);
        const f4u B3 = *(const f4u*)(pb + HW + W + xb);
        const float dA0 = A0.x * xw.x + A0.y * xw.y + A0.z * xw.z + A0.w * xw.w;
        const float dA1 = A1.x * xw.x + A1.y * xw.y + A1.z * xw.z + A1.w * xw.w;
        const float dA2 = A2.x * xw.x + A2.y * xw.y + A2.z * xw.z + A2.w * xw.w;
        const float dA3 = A3.x * xw.x + A3.y * xw.y + A3.z * xw.z + A3.w * xw.w;
        const float dB0 = B0.x * xw.x + B0.y * xw.y + B0.z * xw.z + B0.w * xw.w;
        const float dB1 = B1.x * xw.x + B1.y * xw.y + B1.z * xw.z + B1.w * xw.w;
        const float dB2 = B2.x * xw.x + B2.y * xw.y + B2.z * xw.z + B2.w * xw.w;
        const float dB3 = B3.x * xw.x + B3.y * xw.y + B3.z * xw.z + B3.w * xw.w;
        o0 = yA.z * dA0 + yA.w * dA1 + yB.x * dA2 + yB.y * dA3;
        o1 = yA.z * dB0 + yA.w * dB1 + yB.x * dB2 + yB.y * dB3;
    } else {
        const float4 xp = sdxP[pw];
        const float2 xq = sdxQ[pw];
        const int ia = __float_as_int(xp.x);
        const int ib = __float_as_int(xp.y);
        const float2 a0 = *(const float2*)(pa + ia);
        const float2 b0 = *(const float2*)(pa + ib);
        const float2 a1 = *(const float2*)(pa + W + ia);
        const float2 b1 = *(const float2*)(pa + W + ib);
        const float2 a2 = *(const float2*)(pb + ia);
        const float2 b2 = *(const float2*)(pb + ib);
        const float2 a3 = *(const float2*)(pb + W + ia);
        const float2 b3 = *(const float2*)(pb + W + ib);
        const float2 c0 = *(const float2*)(pa + HW + ia);
        const float2 e0 = *(const float2*)(pa + HW + ib);
        const float2 c1 = *(const float2*)(pa + HW + W + ia);
        const float2 e1 = *(const float2*)(pa + HW + W + ib);
        const float2 c2 = *(const float2*)(pb + HW + ia);
        const float2 e2 = *(const float2*)(pb + HW + ib);
        const float2 c3 = *(const float2*)(pb + HW + W + ia);
        const float2 e3 = *(const float2*)(pb + HW + W + ib);
        const float dA0 = a0.x * xp.z + a0.y * xp.w + b0.x * xq.x + b0.y * xq.y;
        const float dA1 = a1.x * xp.z + a1.y * xp.w + b1.x * xq.x + b1.y * xq.y;
        const float dA2 = a2.x * xp.z + a2.y * xp.w + b2.x * xq.x + b2.y * xq.y;
        const float dA3 = a3.x * xp.z + a3.y * xp.w + b3.x * xq.x + b3.y * xq.y;
        const float dB0 = c0.x * xp.z + c0.y * xp.w + e0.x * xq.x + e0.y * xq.y;
        const float dB1 = c1.x * xp.z + c1.y * xp.w + e1.x * xq.x + e1.y * xq.y;
        const float dB2 = c2.x * xp.z + c2.y * xp.w + e2.x * xq.x + e2.y * xq.y;
        const float dB3 = c3.x * xp.z + c3.y * xp.w + e3.x * xq.x + e3.y * xq.y;
        o0 = yA.z * dA0 + yA.w * dA1 + yB.x * dA2 + yB.y * dA3;
        o1 = yA.z * dB0 + yA.w * dB1 + yB.x * dB2 + yB.y * dB3;
    }

    // out[(r, 2cp, bin)] and out[(r, 2cp+1, bin)]
    float* const obase = out + (size_t)r * ROI_ELEMS + (size_t)(2 * cp) * BINS + bin;
    obase[0]    = o0;
    obase[BINS] = o1;
}

extern "C" void kernel_launch(void* const* d_in, const int* in_sizes, int n_in,
                              void* d_out, int out_size, void* d_ws, size_t ws_size,
                              hipStream_t stream) {
    const float* x2    = (const float*)d_in[0];
    const float* x3    = (const float*)d_in[1];
    const float* x4    = (const float*)d_in[2];
    const float* x5    = (const float*)d_in[3];
    const float* boxes = (const float*)d_in[4];
    float* out = (float*)d_out;

    dim3 grid(NROI, NCHUNK);
    roi_pool_kernel<<<grid, 256, 0, stream>>>(x2, x3, x4, x5, boxes, out);
}